// Round 2
// baseline (2196.034 us; speedup 1.0000x reference)
//
#include <hip/hip_runtime.h>
#include <hip/hip_bf16.h>
#include <math.h>

#define Bk 8
#define Nk 10000
#define Hk 64
#define Lk 4
#define Rk 3
#define Ek 200000
#define FPk 2048

// ---------------------------------------------------------------------------
// CSR build: zero degrees, count, scan, fill
// ---------------------------------------------------------------------------
__global__ void k_zero(int* p, int n){
    int i = blockIdx.x*256 + threadIdx.x;
    if(i < n) p[i] = 0;
}

__global__ void k_count(const int* edge_index, int* deg){
    int idx = blockIdx.x*256 + threadIdx.x;
    if(idx >= Rk*Ek) return;
    int r = idx / Ek, e = idx % Ek;
    int dst = edge_index[r*2*Ek + Ek + e];
    atomicAdd(&deg[r*Nk + dst], 1);
}

__global__ void k_scan(const int* deg, int* offs, int* cursor){
    int r = blockIdx.x;
    __shared__ int s[1024];
    __shared__ int carry;
    if(threadIdx.x == 0) carry = 0;
    __syncthreads();
    for(int base = 0; base < Nk; base += 1024){
        int i = base + threadIdx.x;
        int v = (i < Nk) ? deg[r*Nk + i] : 0;
        s[threadIdx.x] = v;
        __syncthreads();
        for(int d = 1; d < 1024; d <<= 1){
            int t = (threadIdx.x >= d) ? s[threadIdx.x - d] : 0;
            __syncthreads();
            s[threadIdx.x] += t;
            __syncthreads();
        }
        int incl = s[threadIdx.x];
        int excl = carry + incl - v;
        if(i < Nk){ offs[r*(Nk+1)+i] = excl; cursor[r*Nk+i] = excl; }
        __syncthreads();
        if(threadIdx.x == 1023) carry += s[1023];
        __syncthreads();
    }
    if(threadIdx.x == 0) offs[r*(Nk+1)+Nk] = carry;
}

__global__ void k_fill(const int* edge_index, const float* edge_weight,
                       int* cursor, int* ssrc, float* sw){
    int idx = blockIdx.x*256 + threadIdx.x;
    if(idx >= Rk*Ek) return;
    int r = idx / Ek, e = idx % Ek;
    int src = edge_index[r*2*Ek + e];
    int dst = edge_index[r*2*Ek + Ek + e];
    int pos = atomicAdd(&cursor[r*Nk + dst], 1);
    ssrc[r*Ek + pos] = src;
    sw[r*Ek + pos]   = edge_weight[r*Ek + e];
}

// ---------------------------------------------------------------------------
// FiLM: hid = relu(fp @ W1 + b1); film = hid @ W2 + b2; gamma1p=1+tanh, beta
// ---------------------------------------------------------------------------
__global__ void k_film1(const float* fp, const float* W1, const float* b1, float* hid){
    int b = blockIdx.x;
    int h = threadIdx.x & 63, q = threadIdx.x >> 6;
    float acc = 0.f;
    const float* fpb = fp + b*FPk;
    for(int k = q*512; k < (q+1)*512; ++k)
        acc += fpb[k] * W1[k*64 + h];
    __shared__ float red[256];
    red[threadIdx.x] = acc;
    __syncthreads();
    if(q == 0){
        float v = red[h] + red[64+h] + red[128+h] + red[192+h] + b1[h];
        hid[b*64 + h] = fmaxf(v, 0.f);
    }
}

__global__ void k_film2(const float* hid, const float* W2, const float* b2,
                        float* g1p, float* beta){
    int b = blockIdx.x, j = threadIdx.x;   // 128 threads
    float acc = b2[j];
    for(int k = 0; k < 64; ++k)
        acc += hid[b*64 + k] * W2[k*128 + j];
    if(j < 64) g1p[b*64 + j] = 1.f + tanhf(acc);
    else       beta[b*64 + j - 64] = acc;
}

// ---------------------------------------------------------------------------
// x0 = relu(ctl*Wse+bse) + relu(dt*Wse+bse) + cell_emb[cell]; FiLM applied
// ---------------------------------------------------------------------------
__global__ void k_init(const float* ctl, const float* dt, const int* cell_idx,
                       const float* W_se, const float* b_se, const float* cell_emb,
                       const float* g1p, const float* beta, float* x){
    const size_t total = (size_t)Bk*Nk*64;
    for(size_t i = (size_t)blockIdx.x*256 + threadIdx.x; i < total; i += (size_t)gridDim.x*256){
        int h = (int)(i & 63);
        size_t bn = i >> 6;
        int b = (int)(bn / Nk);
        float w = W_se[h], bs = b_se[h];
        float v = fmaxf(ctl[bn]*w + bs, 0.f) + fmaxf(dt[bn]*w + bs, 0.f)
                + cell_emb[cell_idx[b]*64 + h];
        x[i] = v * g1p[b*64 + h] + beta[b*64 + h];
    }
}

// ---------------------------------------------------------------------------
// agg[r][b][dst][h] = sum_{e in CSR_r[dst]} w_e * x[b][src_e][h]
// one wave per (r,b,dst); lane = h
// ---------------------------------------------------------------------------
__global__ __launch_bounds__(256) void k_agg(const float* __restrict__ x,
                      const int* __restrict__ offs, const int* __restrict__ ssrc,
                      const float* __restrict__ sw, float* __restrict__ agg){
    int wid = (blockIdx.x*256 + threadIdx.x) >> 6;     // 0 .. R*B*N-1
    if(wid >= Rk*Bk*Nk) return;
    int lane = threadIdx.x & 63;
    int dst = wid % Nk;
    int t = wid / Nk;
    int b = t % Bk, r = t / Bk;
    int o0 = offs[r*(Nk+1) + dst], o1 = offs[r*(Nk+1) + dst + 1];
    const float* xb = x + (size_t)b*Nk*64;
    const int* sp = ssrc + (size_t)r*Ek;
    const float* wp = sw + (size_t)r*Ek;
    float acc = 0.f;
    for(int e = o0; e < o1; ++e){
        int s = sp[e];
        float w = wp[e];
        acc += w * xb[(size_t)s*64 + lane];
    }
    agg[((((size_t)r*Bk + b)*Nk + dst)*64) + lane] = acc;
}

// ---------------------------------------------------------------------------
// out = x@Wself[l] + sum_r agg_r@Wrel[l,r]; LayerNorm(eps=1e-3); ReLU; x<-out
// block: 256 thr = 4 waves; 32 nodes/block; 8 nodes per thread (reg-blocked)
// ---------------------------------------------------------------------------
__global__ __launch_bounds__(256) void k_proj_ln(float* __restrict__ x,
                      const float* __restrict__ agg,
                      const float* __restrict__ Wself, const float* __restrict__ Wrel,
                      const float* __restrict__ ln_g, const float* __restrict__ ln_b,
                      int l){
    __shared__ float Wl[4096];        // 16 KB, one 64x64 matrix at a time
    __shared__ float In[4*2048];      // 32 KB: [mat][node(32)][k(64)]
    int c  = threadIdx.x & 63;
    int wq = threadIdx.x >> 6;        // wave id 0..3
    int b  = blockIdx.y;
    int node0 = blockIdx.x * 32;
    int nvalid = Nk - node0; if(nvalid > 32) nvalid = 32;
    int lim = nvalid * 64;

    const float* xsrc = x + ((size_t)b*Nk + node0)*64;
    for(int i = threadIdx.x; i < lim; i += 256) In[i] = xsrc[i];
    for(int r = 0; r < 3; ++r){
        const float* asrc = agg + (((size_t)r*Bk + b)*Nk + node0)*64;
        for(int i = threadIdx.x; i < lim; i += 256) In[(r+1)*2048 + i] = asrc[i];
    }

    float gc = ln_g[l*64 + c], bc = ln_b[l*64 + c];
    float acc[8];
    #pragma unroll
    for(int m = 0; m < 8; ++m) acc[m] = 0.f;

    for(int mat = 0; mat < 4; ++mat){
        const float* Wp = (mat == 0) ? (Wself + (size_t)l*4096)
                                     : (Wrel + ((size_t)(l*3 + (mat-1)))*4096);
        __syncthreads();
        for(int i = threadIdx.x; i < 4096; i += 256) Wl[i] = Wp[i];
        __syncthreads();
        const float* inb = &In[mat*2048 + wq*8*64];
        for(int k = 0; k < 64; ++k){
            float w = Wl[k*64 + c];
            #pragma unroll
            for(int m = 0; m < 8; ++m)
                acc[m] += inb[m*64 + k] * w;
        }
    }

    // LayerNorm + ReLU; wave handles nodes node0+wq*8 .. +7, lane c = feature
    float* xdst = x + (size_t)b*Nk*64;
    #pragma unroll
    for(int m = 0; m < 8; ++m){
        int node = node0 + wq*8 + m;
        float v = acc[m];
        float s = v;
        #pragma unroll
        for(int off = 32; off; off >>= 1) s += __shfl_xor(s, off);
        float mu = s * 0.015625f;
        float d = v - mu;
        float s2 = d*d;
        #pragma unroll
        for(int off = 32; off; off >>= 1) s2 += __shfl_xor(s2, off);
        float o = d * rsqrtf(s2*0.015625f + 1e-3f) * gc + bc;
        if(node < Nk) xdst[(size_t)node*64 + c] = fmaxf(o, 0.f);
    }
}

// ---------------------------------------------------------------------------
// out[b,n] = dot(x[b,n,:], W_out) + b_out
// ---------------------------------------------------------------------------
__global__ void k_final(const float* __restrict__ x, const float* __restrict__ W_out,
                        const float* __restrict__ b_out, float* __restrict__ out){
    int wid = (blockIdx.x*256 + threadIdx.x) >> 6;
    int lane = threadIdx.x & 63;
    int nwaves = gridDim.x * 4;
    float w = W_out[lane];
    float bo = b_out[0];
    for(int node = wid; node < Bk*Nk; node += nwaves){
        float v = x[(size_t)node*64 + lane] * w;
        #pragma unroll
        for(int off = 32; off; off >>= 1) v += __shfl_xor(v, off);
        if(lane == 0) out[node] = v + bo;
    }
}

// ---------------------------------------------------------------------------
extern "C" void kernel_launch(void* const* d_in, const int* in_sizes, int n_in,
                              void* d_out, int out_size, void* d_ws, size_t ws_size,
                              hipStream_t stream){
    const float* ctl        = (const float*)d_in[0];
    const float* dt         = (const float*)d_in[1];
    const float* drug_fp    = (const float*)d_in[2];
    const float* edge_w     = (const float*)d_in[3];
    const int*   cell_idx   = (const int*)  d_in[4];
    const int*   edge_index = (const int*)  d_in[5];
    const float* W_se       = (const float*)d_in[6];
    const float* b_se       = (const float*)d_in[7];
    const float* cell_emb   = (const float*)d_in[8];
    const float* W_f1       = (const float*)d_in[9];
    const float* b_f1       = (const float*)d_in[10];
    const float* W_f2       = (const float*)d_in[11];
    const float* b_f2       = (const float*)d_in[12];
    const float* Wself      = (const float*)d_in[13];
    const float* Wrel       = (const float*)d_in[14];
    const float* ln_g       = (const float*)d_in[15];
    const float* ln_b       = (const float*)d_in[16];
    const float* W_out      = (const float*)d_in[17];
    const float* b_out      = (const float*)d_in[18];
    float* out = (float*)d_out;

    char* p = (char*)d_ws;
    auto alloc = [&](size_t bytes)->char*{
        char* r = p; p += (bytes + 255) & ~(size_t)255; return r;
    };
    int*   deg    = (int*)  alloc((size_t)Rk*Nk*4);
    int*   cursor = (int*)  alloc((size_t)Rk*Nk*4);
    int*   offs   = (int*)  alloc((size_t)Rk*(Nk+1)*4);
    int*   ssrc   = (int*)  alloc((size_t)Rk*Ek*4);
    float* sw     = (float*)alloc((size_t)Rk*Ek*4);
    float* hid    = (float*)alloc((size_t)Bk*64*4);
    float* g1p    = (float*)alloc((size_t)Bk*64*4);
    float* beta   = (float*)alloc((size_t)Bk*64*4);
    float* x      = (float*)alloc((size_t)Bk*Nk*64*4);
    float* agg    = (float*)alloc((size_t)3*Bk*Nk*64*4);

    // CSR build (edge structure is layer-invariant; rebuilt every launch)
    k_zero<<<(Rk*Nk + 255)/256, 256, 0, stream>>>(deg, Rk*Nk);
    k_count<<<(Rk*Ek + 255)/256, 256, 0, stream>>>(edge_index, deg);
    k_scan<<<Rk, 1024, 0, stream>>>(deg, offs, cursor);
    k_fill<<<(Rk*Ek + 255)/256, 256, 0, stream>>>(edge_index, edge_w, cursor, ssrc, sw);

    // FiLM
    k_film1<<<Bk, 256, 0, stream>>>(drug_fp, W_f1, b_f1, hid);
    k_film2<<<Bk, 128, 0, stream>>>(hid, W_f2, b_f2, g1p, beta);

    // x0
    k_init<<<2048, 256, 0, stream>>>(ctl, dt, cell_idx, W_se, b_se, cell_emb, g1p, beta, x);

    // layers
    for(int l = 0; l < Lk; ++l){
        // one wave per (r,b,dst): R*B*N = 240000 waves, 4 waves/block -> 60000 blocks
        k_agg<<<(Rk*Bk*Nk + 3)/4, 256, 0, stream>>>(x, offs, ssrc, sw, agg);
        k_proj_ln<<<dim3((Nk + 31)/32, Bk), 256, 0, stream>>>(x, agg, Wself, Wrel, ln_g, ln_b, l);
    }

    // readout
    k_final<<<512, 256, 0, stream>>>(x, W_out, b_out, out);
}

// Round 3
// 1460.298 us; speedup vs baseline: 1.5038x; 1.5038x over previous
//
#include <hip/hip_runtime.h>
#include <hip/hip_bf16.h>
#include <math.h>

#define Bk 8
#define Nk 10000
#define Hk 64
#define Lk 4
#define Rk 3
#define Ek 200000
#define FPk 2048

// ---------------------------------------------------------------------------
// CSR build: zero degrees, count, scan, fill
// ---------------------------------------------------------------------------
__global__ void k_zero(int* p, int n){
    int i = blockIdx.x*256 + threadIdx.x;
    if(i < n) p[i] = 0;
}

__global__ void k_count(const int* edge_index, int* deg){
    int idx = blockIdx.x*256 + threadIdx.x;
    if(idx >= Rk*Ek) return;
    int r = idx / Ek, e = idx % Ek;
    int dst = edge_index[r*2*Ek + Ek + e];
    atomicAdd(&deg[r*Nk + dst], 1);
}

__global__ void k_scan(const int* deg, int* offs, int* cursor){
    int r = blockIdx.x;
    __shared__ int s[1024];
    __shared__ int carry;
    if(threadIdx.x == 0) carry = 0;
    __syncthreads();
    for(int base = 0; base < Nk; base += 1024){
        int i = base + threadIdx.x;
        int v = (i < Nk) ? deg[r*Nk + i] : 0;
        s[threadIdx.x] = v;
        __syncthreads();
        for(int d = 1; d < 1024; d <<= 1){
            int t = (threadIdx.x >= d) ? s[threadIdx.x - d] : 0;
            __syncthreads();
            s[threadIdx.x] += t;
            __syncthreads();
        }
        int incl = s[threadIdx.x];
        int excl = carry + incl - v;
        if(i < Nk){ offs[r*(Nk+1)+i] = excl; cursor[r*Nk+i] = excl; }
        __syncthreads();
        if(threadIdx.x == 1023) carry += s[1023];
        __syncthreads();
    }
    if(threadIdx.x == 0) offs[r*(Nk+1)+Nk] = carry;
}

__global__ void k_fill(const int* edge_index, const float* edge_weight,
                       int* cursor, int* ssrc, float* sw){
    int idx = blockIdx.x*256 + threadIdx.x;
    if(idx >= Rk*Ek) return;
    int r = idx / Ek, e = idx % Ek;
    int src = edge_index[r*2*Ek + e];
    int dst = edge_index[r*2*Ek + Ek + e];
    int pos = atomicAdd(&cursor[r*Nk + dst], 1);
    ssrc[r*Ek + pos] = src;
    sw[r*Ek + pos]   = edge_weight[r*Ek + e];
}

// ---------------------------------------------------------------------------
// FiLM: hid = relu(fp @ W1 + b1); film = hid @ W2 + b2; gamma1p=1+tanh, beta
// ---------------------------------------------------------------------------
__global__ void k_film1(const float* fp, const float* W1, const float* b1, float* hid){
    int b = blockIdx.x;
    int h = threadIdx.x & 63, q = threadIdx.x >> 6;
    float acc = 0.f;
    const float* fpb = fp + b*FPk;
    for(int k = q*512; k < (q+1)*512; ++k)
        acc += fpb[k] * W1[k*64 + h];
    __shared__ float red[256];
    red[threadIdx.x] = acc;
    __syncthreads();
    if(q == 0){
        float v = red[h] + red[64+h] + red[128+h] + red[192+h] + b1[h];
        hid[b*64 + h] = fmaxf(v, 0.f);
    }
}

__global__ void k_film2(const float* hid, const float* W2, const float* b2,
                        float* g1p, float* beta){
    int b = blockIdx.x, j = threadIdx.x;   // 128 threads
    float acc = b2[j];
    for(int k = 0; k < 64; ++k)
        acc += hid[b*64 + k] * W2[k*128 + j];
    if(j < 64) g1p[b*64 + j] = 1.f + tanhf(acc);
    else       beta[b*64 + j - 64] = acc;
}

// ---------------------------------------------------------------------------
// x0 = relu(ctl*Wse+bse) + relu(dt*Wse+bse) + cell_emb[cell]; FiLM applied
// ---------------------------------------------------------------------------
__global__ void k_init(const float* ctl, const float* dt, const int* cell_idx,
                       const float* W_se, const float* b_se, const float* cell_emb,
                       const float* g1p, const float* beta, float* x){
    const size_t total = (size_t)Bk*Nk*64;
    for(size_t i = (size_t)blockIdx.x*256 + threadIdx.x; i < total; i += (size_t)gridDim.x*256){
        int h = (int)(i & 63);
        size_t bn = i >> 6;
        int b = (int)(bn / Nk);
        float w = W_se[h], bs = b_se[h];
        float v = fmaxf(ctl[bn]*w + bs, 0.f) + fmaxf(dt[bn]*w + bs, 0.f)
                + cell_emb[cell_idx[b]*64 + h];
        x[i] = v * g1p[b*64 + h] + beta[b*64 + h];
    }
}

// ---------------------------------------------------------------------------
// agg[r][b][dst][h] = sum_{e in CSR_r[dst]} w_e * x[b][src_e][h]
// one wave per (r,dst), ALL 8 batches per wave; lane = h.
// Adjacency (src,w) fetched cooperatively (one coalesced load per 64 edges),
// broadcast by __shfl; per edge 8 independent 256B gathers -> high MLP.
// ---------------------------------------------------------------------------
__global__ __launch_bounds__(256) void k_agg(const float* __restrict__ x,
                      const int* __restrict__ offs, const int* __restrict__ ssrc,
                      const float* __restrict__ sw, float* __restrict__ agg){
    int wid = (blockIdx.x*256 + threadIdx.x) >> 6;     // 0 .. R*N-1
    if(wid >= Rk*Nk) return;
    int lane = threadIdx.x & 63;
    int r = wid / Nk, dst = wid % Nk;
    int o0 = offs[r*(Nk+1) + dst], o1 = offs[r*(Nk+1) + dst + 1];
    const int* sp = ssrc + (size_t)r*Ek;
    const float* wp = sw + (size_t)r*Ek;

    float acc[8];
    #pragma unroll
    for(int b = 0; b < 8; ++b) acc[b] = 0.f;

    for(int base = o0; base < o1; base += 64){
        int j = base + lane;
        int   svec = (j < o1) ? sp[j] : 0;
        float wvec = (j < o1) ? wp[j] : 0.f;
        int cnt = o1 - base; if(cnt > 64) cnt = 64;
        for(int t = 0; t < cnt; ++t){
            int   s = __shfl(svec, t);
            float w = __shfl(wvec, t);
            const float* row = x + (size_t)s*64 + lane;
            #pragma unroll
            for(int b = 0; b < 8; ++b)
                acc[b] += w * row[(size_t)b*Nk*64];
        }
    }
    #pragma unroll
    for(int b = 0; b < 8; ++b)
        agg[(((size_t)r*Bk + b)*Nk + dst)*64 + lane] = acc[b];
}

// ---------------------------------------------------------------------------
// out = x@Wself[l] + sum_r agg_r@Wrel[l,r]; LayerNorm(eps=1e-3); ReLU; x<-out
// block: 256 thr = 4 waves; 32 nodes/block; 8 nodes per thread (reg-blocked)
// In reads via float4 (ds_read_b128) to cut LDS instruction issue ~2x.
// ---------------------------------------------------------------------------
__global__ __launch_bounds__(256) void k_proj_ln(float* __restrict__ x,
                      const float* __restrict__ agg,
                      const float* __restrict__ Wself, const float* __restrict__ Wrel,
                      const float* __restrict__ ln_g, const float* __restrict__ ln_b,
                      int l){
    __shared__ float Wl[4096];        // 16 KB, one 64x64 matrix at a time
    __shared__ float In[4*2048];      // 32 KB: [mat][node(32)][k(64)]
    int c  = threadIdx.x & 63;
    int wq = threadIdx.x >> 6;        // wave id 0..3
    int b  = blockIdx.y;
    int node0 = blockIdx.x * 32;
    int nvalid = Nk - node0; if(nvalid > 32) nvalid = 32;
    int lim = nvalid * 64;

    const float* xsrc = x + ((size_t)b*Nk + node0)*64;
    for(int i = threadIdx.x; i < lim; i += 256) In[i] = xsrc[i];
    for(int r = 0; r < 3; ++r){
        const float* asrc = agg + (((size_t)r*Bk + b)*Nk + node0)*64;
        for(int i = threadIdx.x; i < lim; i += 256) In[(r+1)*2048 + i] = asrc[i];
    }

    float gc = ln_g[l*64 + c], bc = ln_b[l*64 + c];
    float acc[8];
    #pragma unroll
    for(int m = 0; m < 8; ++m) acc[m] = 0.f;

    for(int mat = 0; mat < 4; ++mat){
        const float* Wp = (mat == 0) ? (Wself + (size_t)l*4096)
                                     : (Wrel + ((size_t)(l*3 + (mat-1)))*4096);
        __syncthreads();
        for(int i = threadIdx.x; i < 4096; i += 256) Wl[i] = Wp[i];
        __syncthreads();
        const float* inb = &In[mat*2048 + wq*8*64];
        for(int k = 0; k < 64; k += 4){
            float w0 = Wl[(k+0)*64 + c];
            float w1 = Wl[(k+1)*64 + c];
            float w2 = Wl[(k+2)*64 + c];
            float w3 = Wl[(k+3)*64 + c];
            #pragma unroll
            for(int m = 0; m < 8; ++m){
                const float4 iv = *(const float4*)&inb[m*64 + k];
                acc[m] += iv.x*w0 + iv.y*w1 + iv.z*w2 + iv.w*w3;
            }
        }
    }

    // LayerNorm + ReLU; wave handles nodes node0+wq*8 .. +7, lane c = feature
    float* xdst = x + (size_t)b*Nk*64;
    #pragma unroll
    for(int m = 0; m < 8; ++m){
        int node = node0 + wq*8 + m;
        float v = acc[m];
        float s = v;
        #pragma unroll
        for(int off = 32; off; off >>= 1) s += __shfl_xor(s, off);
        float mu = s * 0.015625f;
        float d = v - mu;
        float s2 = d*d;
        #pragma unroll
        for(int off = 32; off; off >>= 1) s2 += __shfl_xor(s2, off);
        float o = d * rsqrtf(s2*0.015625f + 1e-3f) * gc + bc;
        if(node < Nk) xdst[(size_t)node*64 + c] = fmaxf(o, 0.f);
    }
}

// ---------------------------------------------------------------------------
// out[b,n] = dot(x[b,n,:], W_out) + b_out
// ---------------------------------------------------------------------------
__global__ void k_final(const float* __restrict__ x, const float* __restrict__ W_out,
                        const float* __restrict__ b_out, float* __restrict__ out){
    int wid = (blockIdx.x*256 + threadIdx.x) >> 6;
    int lane = threadIdx.x & 63;
    int nwaves = gridDim.x * 4;
    float w = W_out[lane];
    float bo = b_out[0];
    for(int node = wid; node < Bk*Nk; node += nwaves){
        float v = x[(size_t)node*64 + lane] * w;
        #pragma unroll
        for(int off = 32; off; off >>= 1) v += __shfl_xor(v, off);
        if(lane == 0) out[node] = v + bo;
    }
}

// ---------------------------------------------------------------------------
extern "C" void kernel_launch(void* const* d_in, const int* in_sizes, int n_in,
                              void* d_out, int out_size, void* d_ws, size_t ws_size,
                              hipStream_t stream){
    const float* ctl        = (const float*)d_in[0];
    const float* dt         = (const float*)d_in[1];
    const float* drug_fp    = (const float*)d_in[2];
    const float* edge_w     = (const float*)d_in[3];
    const int*   cell_idx   = (const int*)  d_in[4];
    const int*   edge_index = (const int*)  d_in[5];
    const float* W_se       = (const float*)d_in[6];
    const float* b_se       = (const float*)d_in[7];
    const float* cell_emb   = (const float*)d_in[8];
    const float* W_f1       = (const float*)d_in[9];
    const float* b_f1       = (const float*)d_in[10];
    const float* W_f2       = (const float*)d_in[11];
    const float* b_f2       = (const float*)d_in[12];
    const float* Wself      = (const float*)d_in[13];
    const float* Wrel       = (const float*)d_in[14];
    const float* ln_g       = (const float*)d_in[15];
    const float* ln_b       = (const float*)d_in[16];
    const float* W_out      = (const float*)d_in[17];
    const float* b_out      = (const float*)d_in[18];
    float* out = (float*)d_out;

    char* p = (char*)d_ws;
    auto alloc = [&](size_t bytes)->char*{
        char* r = p; p += (bytes + 255) & ~(size_t)255; return r;
    };
    int*   deg    = (int*)  alloc((size_t)Rk*Nk*4);
    int*   cursor = (int*)  alloc((size_t)Rk*Nk*4);
    int*   offs   = (int*)  alloc((size_t)Rk*(Nk+1)*4);
    int*   ssrc   = (int*)  alloc((size_t)Rk*Ek*4);
    float* sw     = (float*)alloc((size_t)Rk*Ek*4);
    float* hid    = (float*)alloc((size_t)Bk*64*4);
    float* g1p    = (float*)alloc((size_t)Bk*64*4);
    float* beta   = (float*)alloc((size_t)Bk*64*4);
    float* x      = (float*)alloc((size_t)Bk*Nk*64*4);
    float* agg    = (float*)alloc((size_t)3*Bk*Nk*64*4);

    // CSR build (edge structure is layer-invariant; rebuilt every launch)
    k_zero<<<(Rk*Nk + 255)/256, 256, 0, stream>>>(deg, Rk*Nk);
    k_count<<<(Rk*Ek + 255)/256, 256, 0, stream>>>(edge_index, deg);
    k_scan<<<Rk, 1024, 0, stream>>>(deg, offs, cursor);
    k_fill<<<(Rk*Ek + 255)/256, 256, 0, stream>>>(edge_index, edge_w, cursor, ssrc, sw);

    // FiLM
    k_film1<<<Bk, 256, 0, stream>>>(drug_fp, W_f1, b_f1, hid);
    k_film2<<<Bk, 128, 0, stream>>>(hid, W_f2, b_f2, g1p, beta);

    // x0
    k_init<<<2048, 256, 0, stream>>>(ctl, dt, cell_idx, W_se, b_se, cell_emb, g1p, beta, x);

    // layers
    for(int l = 0; l < Lk; ++l){
        // one wave per (r,dst): R*N = 30000 waves, 4 waves/block -> 7500 blocks
        k_agg<<<(Rk*Nk + 3)/4, 256, 0, stream>>>(x, offs, ssrc, sw, agg);
        k_proj_ln<<<dim3((Nk + 31)/32, Bk), 256, 0, stream>>>(x, agg, Wself, Wrel, ln_g, ln_b, l);
    }

    // readout
    k_final<<<512, 256, 0, stream>>>(x, W_out, b_out, out);
}

// Round 4
// 1089.936 us; speedup vs baseline: 2.0148x; 1.3398x over previous
//
#include <hip/hip_runtime.h>
#include <hip/hip_bf16.h>
#include <math.h>

#define Bk 8
#define Nk 10000
#define Hk 64
#define Lk 4
#define Rk 3
#define Ek 200000
#define FPk 2048

typedef unsigned short u16;
typedef unsigned int   u32;

__device__ __forceinline__ float bf2f(u16 u){
    union{u32 i; float f;} v; v.i = (u32)u << 16; return v.f;
}
__device__ __forceinline__ float bf2f_hi(u32 u){   // high bf16 of packed pair
    union{u32 i; float f;} v; v.i = u & 0xffff0000u; return v.f;
}
__device__ __forceinline__ float bf2f_lo(u32 u){
    union{u32 i; float f;} v; v.i = u << 16; return v.f;
}
__device__ __forceinline__ u16 f2bf(float f){      // round-to-nearest-even
    union{u32 i; float f;} v; v.f = f;
    u32 r = v.i + 0x7fffu + ((v.i >> 16) & 1u);
    return (u16)(r >> 16);
}

// ---------------------------------------------------------------------------
// CSR build
// ---------------------------------------------------------------------------
__global__ void k_zero(int* p, int n){
    int i = blockIdx.x*256 + threadIdx.x;
    if(i < n) p[i] = 0;
}

__global__ void k_count(const int* edge_index, int* deg){
    int idx = blockIdx.x*256 + threadIdx.x;
    if(idx >= Rk*Ek) return;
    int r = idx / Ek, e = idx % Ek;
    int dst = edge_index[r*2*Ek + Ek + e];
    atomicAdd(&deg[r*Nk + dst], 1);
}

__global__ void k_scan(const int* deg, int* offs, int* cursor){
    int r = blockIdx.x;
    __shared__ int s[1024];
    __shared__ int carry;
    if(threadIdx.x == 0) carry = 0;
    __syncthreads();
    for(int base = 0; base < Nk; base += 1024){
        int i = base + threadIdx.x;
        int v = (i < Nk) ? deg[r*Nk + i] : 0;
        s[threadIdx.x] = v;
        __syncthreads();
        for(int d = 1; d < 1024; d <<= 1){
            int t = (threadIdx.x >= d) ? s[threadIdx.x - d] : 0;
            __syncthreads();
            s[threadIdx.x] += t;
            __syncthreads();
        }
        int incl = s[threadIdx.x];
        int excl = carry + incl - v;
        if(i < Nk){ offs[r*(Nk+1)+i] = excl; cursor[r*Nk+i] = excl; }
        __syncthreads();
        if(threadIdx.x == 1023) carry += s[1023];
        __syncthreads();
    }
    if(threadIdx.x == 0) offs[r*(Nk+1)+Nk] = carry;
}

__global__ void k_fill(const int* edge_index, const float* edge_weight,
                       int* cursor, int* ssrc, float* sw){
    int idx = blockIdx.x*256 + threadIdx.x;
    if(idx >= Rk*Ek) return;
    int r = idx / Ek, e = idx % Ek;
    int src = edge_index[r*2*Ek + e];
    int dst = edge_index[r*2*Ek + Ek + e];
    int pos = atomicAdd(&cursor[r*Nk + dst], 1);
    ssrc[r*Ek + pos] = src;
    sw[r*Ek + pos]   = edge_weight[r*Ek + e];
}

// ---------------------------------------------------------------------------
// FiLM stage 1: one block per (b,h) output; 256-thread dot over FP=2048
// ---------------------------------------------------------------------------
__global__ void k_film1(const float* fp, const float* W1, const float* b1, float* hid){
    int b = blockIdx.x >> 6, h = blockIdx.x & 63;
    const float* fpb = fp + b*FPk;
    float acc = 0.f;
    for(int k = threadIdx.x; k < FPk; k += 256)
        acc += fpb[k] * W1[k*64 + h];
    __shared__ float red[256];
    red[threadIdx.x] = acc;
    __syncthreads();
    for(int s = 128; s >= 1; s >>= 1){
        if(threadIdx.x < s) red[threadIdx.x] += red[threadIdx.x + s];
        __syncthreads();
    }
    if(threadIdx.x == 0) hid[b*64 + h] = fmaxf(red[0] + b1[h], 0.f);
}

__global__ void k_film2(const float* hid, const float* W2, const float* b2,
                        float* g1p, float* beta){
    int b = blockIdx.x, j = threadIdx.x;   // 128 threads
    float acc = b2[j];
    for(int k = 0; k < 64; ++k)
        acc += hid[b*64 + k] * W2[k*128 + j];
    if(j < 64) g1p[b*64 + j] = 1.f + tanhf(acc);
    else       beta[b*64 + j - 64] = acc;
}

// ---------------------------------------------------------------------------
// x0 (bf16): relu(ctl*Wse+bse)+relu(dt*Wse+bse)+cell_emb; FiLM applied
// ---------------------------------------------------------------------------
__global__ void k_init(const float* ctl, const float* dt, const int* cell_idx,
                       const float* W_se, const float* b_se, const float* cell_emb,
                       const float* g1p, const float* beta, u16* xh){
    const size_t total = (size_t)Bk*Nk*64;
    for(size_t i = (size_t)blockIdx.x*256 + threadIdx.x; i < total; i += (size_t)gridDim.x*256){
        int h = (int)(i & 63);
        size_t bn = i >> 6;
        int b = (int)(bn / Nk);
        float w = W_se[h], bs = b_se[h];
        float v = fmaxf(ctl[bn]*w + bs, 0.f) + fmaxf(dt[bn]*w + bs, 0.f)
                + cell_emb[cell_idx[b]*64 + h];
        xh[i] = f2bf(v * g1p[b*64 + h] + beta[b*64 + h]);
    }
}

// ---------------------------------------------------------------------------
// agg (bf16): one wave per (r,dst) with b = blockIdx%8 (XCD round-robin ->
// per-XCD gather working set = one batch's xh = 1.28MB, L2-resident).
// Adjacency broadcast via __shfl; 8-deep load unroll for MLP.
// grid: 60000 blocks = 8 batches x 7500 groups x 4 waves
// ---------------------------------------------------------------------------
__global__ __launch_bounds__(256) void k_agg(const u16* __restrict__ xh,
                      const int* __restrict__ offs, const int* __restrict__ ssrc,
                      const float* __restrict__ sw, u16* __restrict__ aggh){
    int b   = blockIdx.x & 7;
    int grp = blockIdx.x >> 3;                       // 0..7499
    int wid = grp*4 + (threadIdx.x >> 6);            // 0..29999 = (r,dst)
    int lane = threadIdx.x & 63;
    int r = wid / Nk, dst = wid % Nk;
    int o0 = offs[r*(Nk+1) + dst], o1 = offs[r*(Nk+1) + dst + 1];
    const int*   sp = ssrc + (size_t)r*Ek;
    const float* wp = sw   + (size_t)r*Ek;
    const u16*   xb = xh + (size_t)b*Nk*64;

    float acc = 0.f;
    for(int base = o0; base < o1; base += 64){
        int j = base + lane;
        int   svec = (j < o1) ? sp[j] : 0;
        float wvec = (j < o1) ? wp[j] : 0.f;
        int cnt = o1 - base; if(cnt > 64) cnt = 64;
        int t = 0;
        for(; t + 8 <= cnt; t += 8){
            float v0 = bf2f(xb[(__shfl(svec,t+0)<<6) + lane]);
            float v1 = bf2f(xb[(__shfl(svec,t+1)<<6) + lane]);
            float v2 = bf2f(xb[(__shfl(svec,t+2)<<6) + lane]);
            float v3 = bf2f(xb[(__shfl(svec,t+3)<<6) + lane]);
            float v4 = bf2f(xb[(__shfl(svec,t+4)<<6) + lane]);
            float v5 = bf2f(xb[(__shfl(svec,t+5)<<6) + lane]);
            float v6 = bf2f(xb[(__shfl(svec,t+6)<<6) + lane]);
            float v7 = bf2f(xb[(__shfl(svec,t+7)<<6) + lane]);
            acc += __shfl(wvec,t+0)*v0; acc += __shfl(wvec,t+1)*v1;
            acc += __shfl(wvec,t+2)*v2; acc += __shfl(wvec,t+3)*v3;
            acc += __shfl(wvec,t+4)*v4; acc += __shfl(wvec,t+5)*v5;
            acc += __shfl(wvec,t+6)*v6; acc += __shfl(wvec,t+7)*v7;
        }
        for(; t < cnt; ++t){
            int   s = __shfl(svec, t);
            float w = __shfl(wvec, t);
            acc += w * bf2f(xb[(s<<6) + lane]);
        }
    }
    aggh[(((size_t)r*Bk + b)*Nk + dst)*64 + lane] = f2bf(acc);
}

// ---------------------------------------------------------------------------
// out = x@Wself[l] + sum_r agg_r@Wrel[l,r]; LayerNorm; ReLU; xh <- out (bf16)
// bf16 global reads staged to fp32 LDS; fp32 accumulate.
// ---------------------------------------------------------------------------
__global__ __launch_bounds__(256) void k_proj_ln(u16* __restrict__ xh,
                      const u16* __restrict__ aggh,
                      const float* __restrict__ Wself, const float* __restrict__ Wrel,
                      const float* __restrict__ ln_g, const float* __restrict__ ln_b,
                      int l){
    __shared__ float Wl[4096];        // 16 KB
    __shared__ float In[4*2048];      // 32 KB: [mat][node(32)][k(64)]
    int c  = threadIdx.x & 63;
    int wq = threadIdx.x >> 6;
    int b  = blockIdx.y;
    int node0 = blockIdx.x * 32;
    int nvalid = Nk - node0; if(nvalid > 32) nvalid = 32;
    int lim4 = (nvalid * 64) >> 2;    // uint2 (4 bf16) units

    const u16* srcs[4];
    srcs[0] = xh + ((size_t)b*Nk + node0)*64;
    srcs[1] = aggh + (((size_t)0*Bk + b)*Nk + node0)*64;
    srcs[2] = aggh + (((size_t)1*Bk + b)*Nk + node0)*64;
    srcs[3] = aggh + (((size_t)2*Bk + b)*Nk + node0)*64;
    #pragma unroll
    for(int m = 0; m < 4; ++m){
        const uint2* s4 = (const uint2*)srcs[m];
        float* dst = &In[m*2048];
        for(int i = threadIdx.x; i < lim4; i += 256){
            uint2 u = s4[i];
            dst[4*i+0] = bf2f_lo(u.x); dst[4*i+1] = bf2f_hi(u.x);
            dst[4*i+2] = bf2f_lo(u.y); dst[4*i+3] = bf2f_hi(u.y);
        }
    }

    float gc = ln_g[l*64 + c], bc = ln_b[l*64 + c];
    float acc[8];
    #pragma unroll
    for(int m = 0; m < 8; ++m) acc[m] = 0.f;

    for(int mat = 0; mat < 4; ++mat){
        const float* Wp = (mat == 0) ? (Wself + (size_t)l*4096)
                                     : (Wrel + ((size_t)(l*3 + (mat-1)))*4096);
        __syncthreads();
        for(int i = threadIdx.x; i < 4096; i += 256) Wl[i] = Wp[i];
        __syncthreads();
        const float* inb = &In[mat*2048 + wq*8*64];
        for(int k = 0; k < 64; k += 4){
            float w0 = Wl[(k+0)*64 + c];
            float w1 = Wl[(k+1)*64 + c];
            float w2 = Wl[(k+2)*64 + c];
            float w3 = Wl[(k+3)*64 + c];
            #pragma unroll
            for(int m = 0; m < 8; ++m){
                const float4 iv = *(const float4*)&inb[m*64 + k];
                acc[m] += iv.x*w0 + iv.y*w1 + iv.z*w2 + iv.w*w3;
            }
        }
    }

    u16* xdst = xh + (size_t)b*Nk*64;
    #pragma unroll
    for(int m = 0; m < 8; ++m){
        int node = node0 + wq*8 + m;
        float v = acc[m];
        float s = v;
        #pragma unroll
        for(int off = 32; off; off >>= 1) s += __shfl_xor(s, off);
        float mu = s * 0.015625f;
        float d = v - mu;
        float s2 = d*d;
        #pragma unroll
        for(int off = 32; off; off >>= 1) s2 += __shfl_xor(s2, off);
        float o = d * rsqrtf(s2*0.015625f + 1e-3f) * gc + bc;
        if(node < Nk) xdst[(size_t)node*64 + c] = f2bf(fmaxf(o, 0.f));
    }
}

// ---------------------------------------------------------------------------
// out[b,n] = dot(x[b,n,:], W_out) + b_out
// ---------------------------------------------------------------------------
__global__ void k_final(const u16* __restrict__ xh, const float* __restrict__ W_out,
                        const float* __restrict__ b_out, float* __restrict__ out){
    int wid = (blockIdx.x*256 + threadIdx.x) >> 6;
    int lane = threadIdx.x & 63;
    int nwaves = gridDim.x * 4;
    float w = W_out[lane];
    float bo = b_out[0];
    for(int node = wid; node < Bk*Nk; node += nwaves){
        float v = bf2f(xh[(size_t)node*64 + lane]) * w;
        #pragma unroll
        for(int off = 32; off; off >>= 1) v += __shfl_xor(v, off);
        if(lane == 0) out[node] = v + bo;
    }
}

// ---------------------------------------------------------------------------
extern "C" void kernel_launch(void* const* d_in, const int* in_sizes, int n_in,
                              void* d_out, int out_size, void* d_ws, size_t ws_size,
                              hipStream_t stream){
    const float* ctl        = (const float*)d_in[0];
    const float* dt         = (const float*)d_in[1];
    const float* drug_fp    = (const float*)d_in[2];
    const float* edge_w     = (const float*)d_in[3];
    const int*   cell_idx   = (const int*)  d_in[4];
    const int*   edge_index = (const int*)  d_in[5];
    const float* W_se       = (const float*)d_in[6];
    const float* b_se       = (const float*)d_in[7];
    const float* cell_emb   = (const float*)d_in[8];
    const float* W_f1       = (const float*)d_in[9];
    const float* b_f1       = (const float*)d_in[10];
    const float* W_f2       = (const float*)d_in[11];
    const float* b_f2       = (const float*)d_in[12];
    const float* Wself      = (const float*)d_in[13];
    const float* Wrel       = (const float*)d_in[14];
    const float* ln_g       = (const float*)d_in[15];
    const float* ln_b       = (const float*)d_in[16];
    const float* W_out      = (const float*)d_in[17];
    const float* b_out      = (const float*)d_in[18];
    float* out = (float*)d_out;

    char* p = (char*)d_ws;
    auto alloc = [&](size_t bytes)->char*{
        char* r = p; p += (bytes + 255) & ~(size_t)255; return r;
    };
    int*   deg    = (int*)  alloc((size_t)Rk*Nk*4);
    int*   cursor = (int*)  alloc((size_t)Rk*Nk*4);
    int*   offs   = (int*)  alloc((size_t)Rk*(Nk+1)*4);
    int*   ssrc   = (int*)  alloc((size_t)Rk*Ek*4);
    float* sw     = (float*)alloc((size_t)Rk*Ek*4);
    float* hid    = (float*)alloc((size_t)Bk*64*4);
    float* g1p    = (float*)alloc((size_t)Bk*64*4);
    float* beta   = (float*)alloc((size_t)Bk*64*4);
    u16*   xh     = (u16*)  alloc((size_t)Bk*Nk*64*2);
    u16*   aggh   = (u16*)  alloc((size_t)3*Bk*Nk*64*2);

    // CSR build (edge structure is layer-invariant; rebuilt every launch)
    k_zero<<<(Rk*Nk + 255)/256, 256, 0, stream>>>(deg, Rk*Nk);
    k_count<<<(Rk*Ek + 255)/256, 256, 0, stream>>>(edge_index, deg);
    k_scan<<<Rk, 1024, 0, stream>>>(deg, offs, cursor);
    k_fill<<<(Rk*Ek + 255)/256, 256, 0, stream>>>(edge_index, edge_w, cursor, ssrc, sw);

    // FiLM
    k_film1<<<Bk*64, 256, 0, stream>>>(drug_fp, W_f1, b_f1, hid);
    k_film2<<<Bk, 128, 0, stream>>>(hid, W_f2, b_f2, g1p, beta);

    // x0
    k_init<<<2048, 256, 0, stream>>>(ctl, dt, cell_idx, W_se, b_se, cell_emb, g1p, beta, xh);

    // layers
    for(int l = 0; l < Lk; ++l){
        // 8 batches x 7500 groups; b = blockIdx%8 keeps each XCD on one batch
        k_agg<<<8*7500, 256, 0, stream>>>(xh, offs, ssrc, sw, aggh);
        k_proj_ln<<<dim3((Nk + 31)/32, Bk), 256, 0, stream>>>(xh, aggh, Wself, Wrel, ln_g, ln_b, l);
    }

    // readout
    k_final<<<512, 256, 0, stream>>>(xh, W_out, b_out, out);
}

// Round 5
// 713.024 us; speedup vs baseline: 3.0799x; 1.5286x over previous
//
#include <hip/hip_runtime.h>
#include <hip/hip_bf16.h>
#include <math.h>

#define Bk 8
#define Nk 10000
#define Hk 64
#define Lk 4
#define Rk 3
#define Ek 200000
#define FPk 2048

typedef unsigned short u16;
typedef unsigned int   u32;
typedef __attribute__((ext_vector_type(8))) short bf16x8;
typedef __attribute__((ext_vector_type(4))) float f32x4;

__device__ __forceinline__ float bf2f(u16 u){
    union{u32 i; float f;} v; v.i = (u32)u << 16; return v.f;
}
__device__ __forceinline__ u16 f2bf(float f){      // round-to-nearest-even
    union{u32 i; float f;} v; v.f = f;
    u32 r = v.i + 0x7fffu + ((v.i >> 16) & 1u);
    return (u16)(r >> 16);
}

// ---------------------------------------------------------------------------
// CSR build
// ---------------------------------------------------------------------------
__global__ void k_zero(int* p, int n){
    int i = blockIdx.x*256 + threadIdx.x;
    if(i < n) p[i] = 0;
}

__global__ void k_count(const int* edge_index, int* deg){
    int idx = blockIdx.x*256 + threadIdx.x;
    if(idx >= Rk*Ek) return;
    int r = idx / Ek, e = idx % Ek;
    int dst = edge_index[r*2*Ek + Ek + e];
    atomicAdd(&deg[r*Nk + dst], 1);
}

__global__ void k_scan(const int* deg, int* offs, int* cursor){
    int r = blockIdx.x;
    __shared__ int s[1024];
    __shared__ int carry;
    if(threadIdx.x == 0) carry = 0;
    __syncthreads();
    for(int base = 0; base < Nk; base += 1024){
        int i = base + threadIdx.x;
        int v = (i < Nk) ? deg[r*Nk + i] : 0;
        s[threadIdx.x] = v;
        __syncthreads();
        for(int d = 1; d < 1024; d <<= 1){
            int t = (threadIdx.x >= d) ? s[threadIdx.x - d] : 0;
            __syncthreads();
            s[threadIdx.x] += t;
            __syncthreads();
        }
        int incl = s[threadIdx.x];
        int excl = carry + incl - v;
        if(i < Nk){ offs[r*(Nk+1)+i] = excl; cursor[r*Nk+i] = excl; }
        __syncthreads();
        if(threadIdx.x == 1023) carry += s[1023];
        __syncthreads();
    }
    if(threadIdx.x == 0) offs[r*(Nk+1)+Nk] = carry;
}

__global__ void k_fill(const int* edge_index, const float* edge_weight,
                       int* cursor, int* ssrc, float* sw){
    int idx = blockIdx.x*256 + threadIdx.x;
    if(idx >= Rk*Ek) return;
    int r = idx / Ek, e = idx % Ek;
    int src = edge_index[r*2*Ek + e];
    int dst = edge_index[r*2*Ek + Ek + e];
    int pos = atomicAdd(&cursor[r*Nk + dst], 1);
    ssrc[r*Ek + pos] = src;
    sw[r*Ek + pos]   = edge_weight[r*Ek + e];
}

// ---------------------------------------------------------------------------
// Weight prep: W -> MFMA B-operand layout, split hi/lo bf16 (fp32-accurate).
// idx = ((((l*4+mt)*2+kc)*4+jt)*64+lane)*8+j ; B[k][n]: k=kc*32+(lane>>4)*8+j,
// n = jt*16 + (lane&15).
// ---------------------------------------------------------------------------
__global__ void k_wprep(const float* __restrict__ Wself, const float* __restrict__ Wrel,
                        u16* __restrict__ wt_hi, u16* __restrict__ wt_lo){
    int idx = blockIdx.x*256 + threadIdx.x;
    if(idx >= Lk*4*2*4*64*8) return;
    int j    = idx & 7;
    int lane = (idx >> 3) & 63;
    int jt   = (idx >> 9) & 3;
    int kc   = (idx >> 11) & 1;
    int mt   = (idx >> 12) & 3;
    int l    = idx >> 14;
    int k    = kc*32 + (lane >> 4)*8 + j;
    int col  = jt*16 + (lane & 15);
    float w = (mt == 0) ? Wself[(l*64 + k)*64 + col]
                        : Wrel[((l*3 + (mt-1))*64 + k)*64 + col];
    u16 hi = f2bf(w);
    u16 lo = f2bf(w - bf2f(hi));
    wt_hi[idx] = hi;
    wt_lo[idx] = lo;
}

// ---------------------------------------------------------------------------
// FiLM
// ---------------------------------------------------------------------------
__global__ void k_film1(const float* fp, const float* W1, const float* b1, float* hid){
    int b = blockIdx.x >> 6, h = blockIdx.x & 63;
    const float* fpb = fp + b*FPk;
    float acc = 0.f;
    for(int k = threadIdx.x; k < FPk; k += 256)
        acc += fpb[k] * W1[k*64 + h];
    __shared__ float red[256];
    red[threadIdx.x] = acc;
    __syncthreads();
    for(int s = 128; s >= 1; s >>= 1){
        if(threadIdx.x < s) red[threadIdx.x] += red[threadIdx.x + s];
        __syncthreads();
    }
    if(threadIdx.x == 0) hid[b*64 + h] = fmaxf(red[0] + b1[h], 0.f);
}

__global__ void k_film2(const float* hid, const float* W2, const float* b2,
                        float* g1p, float* beta){
    int b = blockIdx.x, j = threadIdx.x;   // 128 threads
    float acc = b2[j];
    for(int k = 0; k < 64; ++k)
        acc += hid[b*64 + k] * W2[k*128 + j];
    if(j < 64) g1p[b*64 + j] = 1.f + tanhf(acc);
    else       beta[b*64 + j - 64] = acc;
}

// ---------------------------------------------------------------------------
// x0 (bf16)
// ---------------------------------------------------------------------------
__global__ void k_init(const float* ctl, const float* dt, const int* cell_idx,
                       const float* W_se, const float* b_se, const float* cell_emb,
                       const float* g1p, const float* beta, u16* xh){
    const size_t total = (size_t)Bk*Nk*64;
    for(size_t i = (size_t)blockIdx.x*256 + threadIdx.x; i < total; i += (size_t)gridDim.x*256){
        int h = (int)(i & 63);
        size_t bn = i >> 6;
        int b = (int)(bn / Nk);
        float w = W_se[h], bs = b_se[h];
        float v = fmaxf(ctl[bn]*w + bs, 0.f) + fmaxf(dt[bn]*w + bs, 0.f)
                + cell_emb[cell_idx[b]*64 + h];
        xh[i] = f2bf(v * g1p[b*64 + h] + beta[b*64 + h]);
    }
}

// ---------------------------------------------------------------------------
// agg (bf16): one wave per (r,dst), b = blockIdx%8 (XCD round-robin)
// ---------------------------------------------------------------------------
__global__ __launch_bounds__(256) void k_agg(const u16* __restrict__ xh,
                      const int* __restrict__ offs, const int* __restrict__ ssrc,
                      const float* __restrict__ sw, u16* __restrict__ aggh){
    int b   = blockIdx.x & 7;
    int grp = blockIdx.x >> 3;                       // 0..7499
    int wid = grp*4 + (threadIdx.x >> 6);            // 0..29999 = (r,dst)
    int lane = threadIdx.x & 63;
    int r = wid / Nk, dst = wid % Nk;
    int o0 = offs[r*(Nk+1) + dst], o1 = offs[r*(Nk+1) + dst + 1];
    const int*   sp = ssrc + (size_t)r*Ek;
    const float* wp = sw   + (size_t)r*Ek;
    const u16*   xb = xh + (size_t)b*Nk*64;

    float acc = 0.f;
    for(int base = o0; base < o1; base += 64){
        int j = base + lane;
        int   svec = (j < o1) ? sp[j] : 0;
        float wvec = (j < o1) ? wp[j] : 0.f;
        int cnt = o1 - base; if(cnt > 64) cnt = 64;
        int t = 0;
        for(; t + 8 <= cnt; t += 8){
            float v0 = bf2f(xb[(__shfl(svec,t+0)<<6) + lane]);
            float v1 = bf2f(xb[(__shfl(svec,t+1)<<6) + lane]);
            float v2 = bf2f(xb[(__shfl(svec,t+2)<<6) + lane]);
            float v3 = bf2f(xb[(__shfl(svec,t+3)<<6) + lane]);
            float v4 = bf2f(xb[(__shfl(svec,t+4)<<6) + lane]);
            float v5 = bf2f(xb[(__shfl(svec,t+5)<<6) + lane]);
            float v6 = bf2f(xb[(__shfl(svec,t+6)<<6) + lane]);
            float v7 = bf2f(xb[(__shfl(svec,t+7)<<6) + lane]);
            acc += __shfl(wvec,t+0)*v0; acc += __shfl(wvec,t+1)*v1;
            acc += __shfl(wvec,t+2)*v2; acc += __shfl(wvec,t+3)*v3;
            acc += __shfl(wvec,t+4)*v4; acc += __shfl(wvec,t+5)*v5;
            acc += __shfl(wvec,t+6)*v6; acc += __shfl(wvec,t+7)*v7;
        }
        for(; t < cnt; ++t){
            int   s = __shfl(svec, t);
            float w = __shfl(wvec, t);
            acc += w * bf2f(xb[(s<<6) + lane]);
        }
    }
    aggh[(((size_t)r*Bk + b)*Nk + dst)*64 + lane] = f2bf(acc);
}

// ---------------------------------------------------------------------------
// MFMA projection + LN + ReLU. Wave = 16 nodes x 64 feats.
// A-frag: A[m=lane&15][k=quad*8+j], 16B contiguous per lane, direct global.
// B-frag: pre-transposed wt_hi/wt_lo (k_wprep). W = hi + lo (fp32-accurate).
// C/D: col=lane&15, row=quad*4+reg. LN via xor-shuffle within 16-lane groups.
// ---------------------------------------------------------------------------
__global__ __launch_bounds__(256) void k_proj_mfma(u16* __restrict__ xh,
        const u16* __restrict__ aggh,
        const u16* __restrict__ wt_hi, const u16* __restrict__ wt_lo,
        const float* __restrict__ ln_g, const float* __restrict__ ln_b, int l){
    int lane = threadIdx.x & 63;
    int wq   = threadIdx.x >> 6;
    int b    = blockIdx.y;
    int n0   = blockIdx.x*64 + wq*16;     // 16 nodes for this wave
    int mrow = lane & 15;
    int kq   = lane >> 4;
    int node_a = n0 + mrow;
    if(node_a >= Nk) node_a = Nk - 1;     // clamp; invalid rows never stored

    f32x4 acc[4];
    #pragma unroll
    for(int jt = 0; jt < 4; ++jt) acc[jt] = (f32x4){0.f,0.f,0.f,0.f};

    const u16* wl_hi = wt_hi + (size_t)l*16384;
    const u16* wl_lo = wt_lo + (size_t)l*16384;

    #pragma unroll
    for(int mt = 0; mt < 4; ++mt){
        const u16* arow = (mt == 0)
            ? xh   + ((size_t)b*Nk + node_a)*64
            : aggh + (((size_t)(mt-1)*Bk + b)*Nk + node_a)*64;
        #pragma unroll
        for(int kc = 0; kc < 2; ++kc){
            bf16x8 afrag = *(const bf16x8*)(arow + kc*32 + kq*8);
            #pragma unroll
            for(int jt = 0; jt < 4; ++jt){
                size_t wi = ((size_t)((mt*2 + kc)*4 + jt)*64 + lane)*8;
                bf16x8 bh = *(const bf16x8*)(wl_hi + wi);
                bf16x8 bl = *(const bf16x8*)(wl_lo + wi);
                acc[jt] = __builtin_amdgcn_mfma_f32_16x16x32_bf16(afrag, bh, acc[jt], 0, 0, 0);
                acc[jt] = __builtin_amdgcn_mfma_f32_16x16x32_bf16(afrag, bl, acc[jt], 0, 0, 0);
            }
        }
    }

    float gv[4], bv[4];
    #pragma unroll
    for(int jt = 0; jt < 4; ++jt){
        int f = jt*16 + mrow;
        gv[jt] = ln_g[l*64 + f];
        bv[jt] = ln_b[l*64 + f];
    }

    u16* xdst = xh + (size_t)b*Nk*64;
    #pragma unroll
    for(int v = 0; v < 4; ++v){
        float s1 = acc[0][v] + acc[1][v] + acc[2][v] + acc[3][v];
        float s2 = acc[0][v]*acc[0][v] + acc[1][v]*acc[1][v]
                 + acc[2][v]*acc[2][v] + acc[3][v]*acc[3][v];
        #pragma unroll
        for(int off = 1; off <= 8; off <<= 1){
            s1 += __shfl_xor(s1, off);
            s2 += __shfl_xor(s2, off);
        }
        float mu  = s1 * 0.015625f;
        float var = s2 * 0.015625f - mu*mu;
        float rstd = rsqrtf(var + 1e-3f);
        int node = n0 + kq*4 + v;
        if(node < Nk){
            #pragma unroll
            for(int jt = 0; jt < 4; ++jt){
                float o = (acc[jt][v] - mu) * rstd * gv[jt] + bv[jt];
                xdst[(size_t)node*64 + jt*16 + mrow] = f2bf(fmaxf(o, 0.f));
            }
        }
    }
}

// ---------------------------------------------------------------------------
// out[b,n] = dot(x[b,n,:], W_out) + b_out
// ---------------------------------------------------------------------------
__global__ void k_final(const u16* __restrict__ xh, const float* __restrict__ W_out,
                        const float* __restrict__ b_out, float* __restrict__ out){
    int wid = (blockIdx.x*256 + threadIdx.x) >> 6;
    int lane = threadIdx.x & 63;
    int nwaves = gridDim.x * 4;
    float w = W_out[lane];
    float bo = b_out[0];
    for(int node = wid; node < Bk*Nk; node += nwaves){
        float v = bf2f(xh[(size_t)node*64 + lane]) * w;
        #pragma unroll
        for(int off = 32; off; off >>= 1) v += __shfl_xor(v, off);
        if(lane == 0) out[node] = v + bo;
    }
}

// ---------------------------------------------------------------------------
extern "C" void kernel_launch(void* const* d_in, const int* in_sizes, int n_in,
                              void* d_out, int out_size, void* d_ws, size_t ws_size,
                              hipStream_t stream){
    const float* ctl        = (const float*)d_in[0];
    const float* dt         = (const float*)d_in[1];
    const float* drug_fp    = (const float*)d_in[2];
    const float* edge_w     = (const float*)d_in[3];
    const int*   cell_idx   = (const int*)  d_in[4];
    const int*   edge_index = (const int*)  d_in[5];
    const float* W_se       = (const float*)d_in[6];
    const float* b_se       = (const float*)d_in[7];
    const float* cell_emb   = (const float*)d_in[8];
    const float* W_f1       = (const float*)d_in[9];
    const float* b_f1       = (const float*)d_in[10];
    const float* W_f2       = (const float*)d_in[11];
    const float* b_f2       = (const float*)d_in[12];
    const float* Wself      = (const float*)d_in[13];
    const float* Wrel       = (const float*)d_in[14];
    const float* ln_g       = (const float*)d_in[15];
    const float* ln_b       = (const float*)d_in[16];
    const float* W_out      = (const float*)d_in[17];
    const float* b_out      = (const float*)d_in[18];
    float* out = (float*)d_out;

    char* p = (char*)d_ws;
    auto alloc = [&](size_t bytes)->char*{
        char* r = p; p += (bytes + 255) & ~(size_t)255; return r;
    };
    int*   deg    = (int*)  alloc((size_t)Rk*Nk*4);
    int*   cursor = (int*)  alloc((size_t)Rk*Nk*4);
    int*   offs   = (int*)  alloc((size_t)Rk*(Nk+1)*4);
    int*   ssrc   = (int*)  alloc((size_t)Rk*Ek*4);
    float* sw     = (float*)alloc((size_t)Rk*Ek*4);
    float* hid    = (float*)alloc((size_t)Bk*64*4);
    float* g1p    = (float*)alloc((size_t)Bk*64*4);
    float* beta   = (float*)alloc((size_t)Bk*64*4);
    u16*   xh     = (u16*)  alloc((size_t)Bk*Nk*64*2);
    u16*   aggh   = (u16*)  alloc((size_t)3*Bk*Nk*64*2);
    u16*   wt_hi  = (u16*)  alloc((size_t)Lk*16384*2);
    u16*   wt_lo  = (u16*)  alloc((size_t)Lk*16384*2);

    // CSR build (edge structure is layer-invariant; rebuilt every launch)
    k_zero<<<(Rk*Nk + 255)/256, 256, 0, stream>>>(deg, Rk*Nk);
    k_count<<<(Rk*Ek + 255)/256, 256, 0, stream>>>(edge_index, deg);
    k_scan<<<Rk, 1024, 0, stream>>>(deg, offs, cursor);
    k_fill<<<(Rk*Ek + 255)/256, 256, 0, stream>>>(edge_index, edge_w, cursor, ssrc, sw);

    // weight prep for MFMA projection (all layers at once)
    k_wprep<<<(Lk*4*2*4*64*8 + 255)/256, 256, 0, stream>>>(Wself, Wrel, wt_hi, wt_lo);

    // FiLM
    k_film1<<<Bk*64, 256, 0, stream>>>(drug_fp, W_f1, b_f1, hid);
    k_film2<<<Bk, 128, 0, stream>>>(hid, W_f2, b_f2, g1p, beta);

    // x0
    k_init<<<2048, 256, 0, stream>>>(ctl, dt, cell_idx, W_se, b_se, cell_emb, g1p, beta, xh);

    // layers
    for(int l = 0; l < Lk; ++l){
        k_agg<<<8*7500, 256, 0, stream>>>(xh, offs, ssrc, sw, aggh);
        k_proj_mfma<<<dim3((Nk + 63)/64, Bk), 256, 0, stream>>>(
            xh, aggh, wt_hi, wt_lo, ln_g, ln_b, l);
    }

    // readout
    k_final<<<512, 256, 0, stream>>>(xh, W_out, b_out, out);
}